// Round 6
// baseline (132.857 us; speedup 1.0000x reference)
//
#include <hip/hip_runtime.h>
#include <hip/hip_bf16.h>
#include <math.h>

typedef __attribute__((ext_vector_type(8))) __bf16 bf16x8;
typedef __attribute__((ext_vector_type(4))) float  f32x4;

constexpr int NROW = 8192;
constexpr int DDIM = 256;
constexpr int KDIM = 512;               // packed [x | e]
constexpr int BM = 256, BN = 128, BK = 32;
constexpr int NT = KDIM / BK;           // 16 K-tiles
constexpr int ABYTES = BM * BK * 2;     // 16 KB
constexpr int BBYTES = BN * BK * 2;     // 8 KB
constexpr int BUFBYTES = ABYTES + BBYTES; // 24 KB; x2 = 48 KB gemm stage
constexpr int NBLK = 1056;              // triangular tile count: sum 2k, k=1..32

__device__ __forceinline__ void gload_lds16(const void* g, void* l) {
  __builtin_amdgcn_global_load_lds(
      (const __attribute__((address_space(1))) void*)g,
      (__attribute__((address_space(3))) void*)l, 16, 0, 0);
}

// ---------------- prep: P = [bf16(x) | bf16(exp(1-dc))], s_i = (1-p)/d*|x_i|^2
__global__ __launch_bounds__(256) void prep_kernel(
    const float* __restrict__ x, const float* __restrict__ dc,
    const float* __restrict__ pparm,
    __hip_bfloat16* __restrict__ P, float* __restrict__ s)
{
  const int row = blockIdx.x;
  const int t   = threadIdx.x;
  const float xv = x[(size_t)row * DDIM + t];
  const float ev = __expf(1.0f - dc[(size_t)row * DDIM + t]);
  P[(size_t)row * KDIM + t]        = __float2bfloat16(xv);
  P[(size_t)row * KDIM + DDIM + t] = __float2bfloat16(ev);

  float v = xv * xv;
  #pragma unroll
  for (int off = 32; off > 0; off >>= 1) v += __shfl_down(v, off, 64);
  __shared__ float red[4];
  const int lane = t & 63, wid = t >> 6;
  if (lane == 0) red[wid] = v;
  __syncthreads();
  if (t == 0) {
    const float p = pparm[0];
    s[row] = (1.0f - p) * (1.0f / (float)DDIM) * (red[0] + red[1] + red[2] + red[3]);
  }
}

// ---------------- symmetric GEMM: compute tiles bj>=2bi only (51.5% area).
// sim[i,j]==sim[j,i] bit-exact (MFMA dot operand-order symmetric), so
// strict-upper tiles (bj>=2bi+2) also write their transposed mirror via a
// 64KB LDS image; straddle tiles (bj=2bi,2bi+1) write direct only.
__global__ void __launch_bounds__(512, 4) adj_gemm(
    const __hip_bfloat16* __restrict__ P, const float* __restrict__ s,
    const float* __restrict__ pparm, float* __restrict__ out)
{
  __shared__ __align__(16) char lds[65536];   // 48 KB gemm stage / 64 KB mirror img

  const float p  = pparm[0];
  const float cx = -2.0f * (1.0f - p) / (float)DDIM;
  const float ce = p / (float)DDIM;
  const float midscale = cx / ce;

  // triangular block index -> (bi, bj): C(bi) = bi*(65-bi), bj = 2bi + rem
  const int orig = blockIdx.x;
  int bi = (int)((65.0f - sqrtf(65.0f * 65.0f - 4.0f * (float)orig)) * 0.5f);
  while (bi > 0 && bi * (65 - bi) > orig) --bi;
  while ((bi + 1) * (65 - (bi + 1)) <= orig) ++bi;
  const int bj = 2 * bi + (orig - bi * (65 - bi));
  const int rowBase = bi * BM;
  const int colBase = bj * BN;
  const bool mirror = (bj >= 2 * bi + 2);

  const int tid  = threadIdx.x;
  const int lane = tid & 63;
  const int wid  = tid >> 6;               // 8 waves: wm = wid>>1 (4), wn = wid&1 (2)
  const int wmrow = (wid >> 1) * 64;
  const int wnrow = (wid & 1) * 64;
  const int frow = lane & 15;
  const int kq   = lane >> 4;
  const int rq   = lane >> 4;

  // K-loop read swizzle: LDS byte (r,c) holds logical (r, c ^ ((r&3)<<4)).
  const int cb = (kq * 16) ^ ((frow & 3) << 4);

  // staging: 2 A-chunks + 1 B-chunk (16 B each); linear dest, pre-swizzled src.
  const int rA0  = tid >> 2;
  const int gcw  = ((tid & 3) * 16) ^ ((rA0 & 3) << 4);
  const char* Pc = (const char*)P;
  const char* gA0 = Pc + (size_t)(rowBase + rA0)       * (KDIM * 2) + gcw;
  const char* gA1 = Pc + (size_t)(rowBase + 128 + rA0) * (KDIM * 2) + gcw;
  const char* gB  = Pc + (size_t)(colBase + rA0)       * (KDIM * 2) + gcw;
  const int dA0 = tid * 16, dA1 = 8192 + tid * 16, dB = ABYTES + tid * 16;

#define STAGE(kk) do {                                   \
    char* _b = lds + ((kk) & 1) * BUFBYTES;              \
    const int _ko = (kk) * (BK * 2);                     \
    gload_lds16(gA0 + _ko, _b + dA0);                    \
    gload_lds16(gA1 + _ko, _b + dA1);                    \
    gload_lds16(gB  + _ko, _b + dB);                     \
  } while (0)

  STAGE(0);
  asm volatile("s_waitcnt vmcnt(0)" ::: "memory");
  asm volatile("s_barrier" ::: "memory");

  f32x4 acc[4][4];
  #pragma unroll
  for (int m = 0; m < 4; ++m)
    #pragma unroll
    for (int n = 0; n < 4; ++n)
      acc[m][n] = (f32x4){0.f, 0.f, 0.f, 0.f};

  #pragma unroll
  for (int t = 0; t < NT; ++t) {
    const char* buf  = lds + (t & 1) * BUFBYTES;
    const char* bufB = buf + ABYTES;

    if (t < NT - 1) STAGE(t + 1);

    bf16x8 a[4], b[4];
    #pragma unroll
    for (int i = 0; i < 4; ++i)
      a[i] = *(const bf16x8*)(buf + (wmrow + i * 16 + frow) * 64 + cb);
    #pragma unroll
    for (int j = 0; j < 4; ++j)
      b[j] = *(const bf16x8*)(bufB + (wnrow + j * 16 + frow) * 64 + cb);

    #pragma unroll
    for (int i = 0; i < 4; ++i)
      #pragma unroll
      for (int j = 0; j < 4; ++j)
        acc[i][j] = __builtin_amdgcn_mfma_f32_16x16x32_bf16(a[i], b[j], acc[i][j], 0, 0, 0);

    if (t == DDIM / BK - 1) {              // x-segment done: acc = Sx -> * cx/ce
      #pragma unroll
      for (int m = 0; m < 4; ++m)
        #pragma unroll
        for (int n = 0; n < 4; ++n)
          acc[m][n] *= midscale;
    }

    if (t < NT - 1) {
      asm volatile("s_waitcnt vmcnt(0)" ::: "memory");
      asm volatile("s_barrier" ::: "memory");
    }
  }

  // ---- epilogue: denom = s_i+s_j+ce*acc; val = 1/denom (diag 1).
  // Direct stores always; mirror tiles also build a 64KB LDS image per
  // 64-col half and store the transpose (rows of out^T, 1KB contiguous/wave).
  float* ldsf = (float*)lds;
  const int st_w = wid & 1;                // LDS strip = wn

  if (mirror) __syncthreads();             // K-loop LDS reads drained

  #pragma unroll
  for (int h = 0; h < 2; ++h) {
    if (mirror && h) __syncthreads();      // h0 gathers done before overwrite
    #pragma unroll
    for (int j = 0; j < 2; ++j) {
      const int n = 2 * h + j;
      const int gcol = colBase + wnrow + n * 16 + frow;
      const float scol = s[gcol];
      #pragma unroll
      for (int m = 0; m < 4; ++m) {
        #pragma unroll
        for (int r = 0; r < 4; ++r) {
          const int R = wmrow + m * 16 + rq * 4 + r;
          const int grow = rowBase + R;
          const float denom = s[grow] + scol + ce * acc[m][n][r];
          const float val = (grow == gcol) ? 1.0f : __builtin_amdgcn_rcpf(denom);
          out[(size_t)grow * NROW + gcol] = val;
          if (mirror) {
            const int c32 = j * 16 + frow;
            const int cc = (c32 + (R >> 2) + 8 * (R & 3)) & 31;
            ldsf[st_w * 8192 + R * 32 + cc] = val;
          }
        }
      }
    }
    if (mirror) {
      __syncthreads();
      // transpose-gather: iter i -> out^T row; lane covers 4 consecutive cols
      #pragma unroll
      for (int i = 0; i < 8; ++i) {
        const int cl  = i * 8 + wid;       // 0..63
        const int st  = cl >> 5;
        const int c32 = cl & 31;
        const int gTrow = colBase + st * 64 + 32 * h + c32;
        f32x4 v;
        #pragma unroll
        for (int r = 0; r < 4; ++r)
          v[r] = ldsf[st * 8192 + (4 * lane + r) * 32 + ((c32 + lane + 8 * r) & 31)];
        *(f32x4*)&out[(size_t)gTrow * NROW + rowBase + 4 * lane] = v;
      }
    }
  }
}

extern "C" void kernel_launch(void* const* d_in, const int* in_sizes, int n_in,
                              void* d_out, int out_size, void* d_ws, size_t ws_size,
                              hipStream_t stream) {
  const float* x  = (const float*)d_in[0];
  const float* dc = (const float*)d_in[1];
  const float* pp = (const float*)d_in[2];
  float* out = (float*)d_out;

  __hip_bfloat16* P = (__hip_bfloat16*)d_ws;                       // 8 MB
  float* s = (float*)((char*)d_ws + (size_t)NROW * KDIM * 2);      // +32 KB

  prep_kernel<<<NROW, 256, 0, stream>>>(x, dc, pp, P, s);
  adj_gemm<<<NBLK, 512, 0, stream>>>(P, s, pp, out);
}

// Round 7
// 117.591 us; speedup vs baseline: 1.1298x; 1.1298x over previous
//
#include <hip/hip_runtime.h>
#include <hip/hip_bf16.h>

typedef __attribute__((ext_vector_type(8))) __bf16 bf16x8;
typedef __attribute__((ext_vector_type(4))) float  f32x4;

constexpr int NROW = 8192;
constexpr int DDIM = 256;
constexpr int KDIM = 512;               // packed [x | e]
constexpr int BM = 256, BN = 128, BK = 32;
constexpr int NT = KDIM / BK;           // 16 K-tiles
constexpr int ABYTES = BM * BK * 2;     // 16 KB
constexpr int BBYTES = BN * BK * 2;     // 8 KB
constexpr int BUFBYTES = ABYTES + BBYTES; // 24 KB; x2 = 48 KB total LDS

__device__ __forceinline__ void gload_lds16(const void* g, void* l) {
  __builtin_amdgcn_global_load_lds(
      (const __attribute__((address_space(1))) void*)g,
      (__attribute__((address_space(3))) void*)l, 16, 0, 0);
}

// ---------------- prep: P = [bf16(x) | bf16(exp(1-dc))], s_i = (1-p)/d*|x_i|^2
__global__ __launch_bounds__(256) void prep_kernel(
    const float* __restrict__ x, const float* __restrict__ dc,
    const float* __restrict__ pparm,
    __hip_bfloat16* __restrict__ P, float* __restrict__ s)
{
  const int row = blockIdx.x;
  const int t   = threadIdx.x;
  const float xv = x[(size_t)row * DDIM + t];
  const float ev = __expf(1.0f - dc[(size_t)row * DDIM + t]);
  P[(size_t)row * KDIM + t]        = __float2bfloat16(xv);
  P[(size_t)row * KDIM + DDIM + t] = __float2bfloat16(ev);

  float v = xv * xv;
  #pragma unroll
  for (int off = 32; off > 0; off >>= 1) v += __shfl_down(v, off, 64);
  __shared__ float red[4];
  const int lane = t & 63, wid = t >> 6;
  if (lane == 0) red[wid] = v;
  __syncthreads();
  if (t == 0) {
    const float p = pparm[0];
    s[row] = (1.0f - p) * (1.0f / (float)DDIM) * (red[0] + red[1] + red[2] + red[3]);
  }
}

// ---------------- GEMM: G = P@P^T segment-scaled; sim = 1/(s_i+s_j+ce*G), diag=1
// Round-4 K-loop (BK=32 dbuf, counted prefetch, 2 blocks/CU). Epilogue: direct
// per-element stores but NON-TEMPORAL (nt): bypass L2/L3 allocate -> no RFO,
// P stays cache-resident. Tests the write-cache-path theory in isolation.
__global__ void __launch_bounds__(512, 4) adj_gemm(
    const __hip_bfloat16* __restrict__ P, const float* __restrict__ s,
    const float* __restrict__ pparm, float* __restrict__ out)
{
  __shared__ __align__(16) char lds[2 * BUFBYTES];

  const float p  = pparm[0];
  const float cx = -2.0f * (1.0f - p) / (float)DDIM;
  const float ce = p / (float)DDIM;
  const float midscale = cx / ce;

  // band-major: 2048 blocks = 32 bands x 64 col-slabs (write locality).
  const int orig = blockIdx.x;
  const int bi = orig >> 6;                // 0..31  (256-row output band)
  const int bj = orig & 63;                // 0..63  (128-col slab)
  const int rowBase = bi * BM;
  const int colBase = bj * BN;

  const int tid  = threadIdx.x;
  const int lane = tid & 63;
  const int wid  = tid >> 6;               // 8 waves: wm = wid>>1 (4), wn = wid&1 (2)
  const int wmrow = (wid >> 1) * 64;
  const int wnrow = (wid & 1) * 64;
  const int frow = lane & 15;
  const int kq   = lane >> 4;

  // read swizzle: LDS byte (r,c) holds logical (r, c ^ ((r&3)<<4)); row = 64 B.
  const int cb = (kq * 16) ^ ((frow & 3) << 4);

  // staging: 2 A-chunks + 1 B-chunk (16 B each); linear dest, pre-swizzled src.
  const int rA0  = tid >> 2;
  const int gcw  = ((tid & 3) * 16) ^ ((rA0 & 3) << 4);
  const char* Pc = (const char*)P;
  const char* gA0 = Pc + (size_t)(rowBase + rA0)       * (KDIM * 2) + gcw;
  const char* gA1 = Pc + (size_t)(rowBase + 128 + rA0) * (KDIM * 2) + gcw;
  const char* gB  = Pc + (size_t)(colBase + rA0)       * (KDIM * 2) + gcw;
  const int dA0 = tid * 16, dA1 = 8192 + tid * 16, dB = ABYTES + tid * 16;

#define STAGE(kk) do {                                   \
    char* _b = lds + ((kk) & 1) * BUFBYTES;              \
    const int _ko = (kk) * (BK * 2);                     \
    gload_lds16(gA0 + _ko, _b + dA0);                    \
    gload_lds16(gA1 + _ko, _b + dA1);                    \
    gload_lds16(gB  + _ko, _b + dB);                     \
  } while (0)

  STAGE(0);
  asm volatile("s_waitcnt vmcnt(0)" ::: "memory");
  asm volatile("s_barrier" ::: "memory");

  f32x4 acc[4][4];
  #pragma unroll
  for (int m = 0; m < 4; ++m)
    #pragma unroll
    for (int n = 0; n < 4; ++n)
      acc[m][n] = (f32x4){0.f, 0.f, 0.f, 0.f};

  #pragma unroll
  for (int t = 0; t < NT; ++t) {
    const char* buf  = lds + (t & 1) * BUFBYTES;
    const char* bufB = buf + ABYTES;

    if (t < NT - 1) STAGE(t + 1);

    bf16x8 a[4], b[4];
    #pragma unroll
    for (int i = 0; i < 4; ++i)
      a[i] = *(const bf16x8*)(buf + (wmrow + i * 16 + frow) * 64 + cb);
    #pragma unroll
    for (int j = 0; j < 4; ++j)
      b[j] = *(const bf16x8*)(bufB + (wnrow + j * 16 + frow) * 64 + cb);

    #pragma unroll
    for (int i = 0; i < 4; ++i)
      #pragma unroll
      for (int j = 0; j < 4; ++j)
        acc[i][j] = __builtin_amdgcn_mfma_f32_16x16x32_bf16(a[i], b[j], acc[i][j], 0, 0, 0);

    if (t == DDIM / BK - 1) {              // x-segment done: acc = Sx -> * cx/ce
      #pragma unroll
      for (int m = 0; m < 4; ++m)
        #pragma unroll
        for (int n = 0; n < 4; ++n)
          acc[m][n] *= midscale;
    }

    if (t < NT - 1) {
      asm volatile("s_waitcnt vmcnt(0)" ::: "memory");
      asm volatile("s_barrier" ::: "memory");
    }
  }

  // ---- epilogue: denom = s_i + s_j + ce*acc ; out = 1/denom (diag 1).
  // Non-temporal stores: no cache allocate / no RFO; P stays L2-resident.
  const int rq = lane >> 4;
  #pragma unroll
  for (int n = 0; n < 4; ++n) {
    const int gcol_o = colBase + wnrow + n * 16 + frow;
    const float scol = s[gcol_o];
    #pragma unroll
    for (int m = 0; m < 4; ++m) {
      const int growb = rowBase + wmrow + m * 16 + rq * 4;
      #pragma unroll
      for (int r = 0; r < 4; ++r) {
        const int grow = growb + r;
        const float denom = s[grow] + scol + ce * acc[m][n][r];
        const float val = (grow == gcol_o) ? 1.0f : __builtin_amdgcn_rcpf(denom);
        __builtin_nontemporal_store(val, &out[(size_t)grow * NROW + gcol_o]);
      }
    }
  }
}

extern "C" void kernel_launch(void* const* d_in, const int* in_sizes, int n_in,
                              void* d_out, int out_size, void* d_ws, size_t ws_size,
                              hipStream_t stream) {
  const float* x  = (const float*)d_in[0];
  const float* dc = (const float*)d_in[1];
  const float* pp = (const float*)d_in[2];
  float* out = (float*)d_out;

  __hip_bfloat16* P = (__hip_bfloat16*)d_ws;                       // 8 MB
  float* s = (float*)((char*)d_ws + (size_t)NROW * KDIM * 2);      // +32 KB

  prep_kernel<<<NROW, 256, 0, stream>>>(x, dc, pp, P, s);
  adj_gemm<<<(NROW / BM) * (NROW / BN), 512, 0, stream>>>(P, s, pp, out);
}